// Round 1
// baseline (684.310 us; speedup 1.0000x reference)
//
#include <hip/hip_runtime.h>
#include <math.h>

#define BATCH 16
#define P 32768
#define C 81
#define CM1 80
#define NCAND 400
#define NOUT 100
#define NBINS 4096
#define CAND_MAX 4096
#define SMIN_F (-16.0f)
#define BIN_SCALE (NBINS / 16.0f)
#define IMG_SZ 512.0f
#define NMS_THR 0.45f
#define NWORDS 7  // ceil(400/64)

// ---- workspace layout (bytes) ----
#define OFF_HIST      0                         // BATCH*NBINS*4 = 262144
#define OFF_CNT       (OFF_HIST + BATCH*NBINS*4)      // BATCH*4
#define OFF_THR       (OFF_CNT + 64)                  // BATCH*4
#define OFF_CVAL      (OFF_THR + 64)                  // BATCH*CAND_MAX*4
#define OFF_CIDX      (OFF_CVAL + BATCH*CAND_MAX*4)   // BATCH*CAND_MAX*4
#define OFF_SVAL      (OFF_CIDX + BATCH*CAND_MAX*4)   // BATCH*NCAND*4
#define OFF_SIDX      (OFF_SVAL + BATCH*NCAND*4)      // BATCH*NCAND*4

__device__ __forceinline__ void row_lse(const float* __restrict__ row,
                                        float r[C], float& m, float& l) {
#pragma unroll
    for (int i = 0; i < C; ++i) r[i] = row[i];
    m = r[0];
#pragma unroll
    for (int i = 1; i < C; ++i) m = fmaxf(m, r[i]);
    float s = 0.0f;
#pragma unroll
    for (int i = 0; i < C; ++i) s += expf(r[i] - m);
    l = logf(s);
}

__device__ __forceinline__ int score_bin(float sc) {
    int b = (int)((sc - SMIN_F) * BIN_SCALE);
    if (b < 0) b = 0;
    if (b > NBINS - 1) b = NBINS - 1;
    return b;
}

__global__ __launch_bounds__(256) void k_score_hist(const float* __restrict__ logits,
                                                    unsigned* __restrict__ hist) {
    __shared__ unsigned lh[NBINS];
    for (int b = threadIdx.x; b < NBINS; b += 256) lh[b] = 0;
    __syncthreads();
    int img = blockIdx.y;
    int p = blockIdx.x * 256 + threadIdx.x;
    const float* row = logits + ((size_t)img * P + p) * C;
    float r[C], m, l;
    row_lse(row, r, m, l);
#pragma unroll
    for (int c = 1; c < C; ++c) {
        float sc = (r[c] - m) - l;
        atomicAdd(&lh[score_bin(sc)], 1u);
    }
    __syncthreads();
    unsigned* gh = hist + (size_t)img * NBINS;
    for (int b = threadIdx.x; b < NBINS; b += 256)
        if (lh[b]) atomicAdd(&gh[b], lh[b]);
}

__global__ void k_find_thresh(const unsigned* __restrict__ hist,
                              unsigned* __restrict__ thr) {
    int img = blockIdx.x;
    if (threadIdx.x == 0) {
        const unsigned* gh = hist + (size_t)img * NBINS;
        unsigned cum = 0;
        int b = NBINS - 1;
        for (; b >= 0; --b) {
            cum += gh[b];
            if (cum >= NCAND) break;
        }
        thr[img] = (b < 0) ? 0u : (unsigned)b;
    }
}

__global__ __launch_bounds__(256) void k_collect(const float* __restrict__ logits,
                                                 const unsigned* __restrict__ thr,
                                                 unsigned* __restrict__ cnt,
                                                 float* __restrict__ cval,
                                                 unsigned* __restrict__ cidx) {
    int img = blockIdx.y;
    int p = blockIdx.x * 256 + threadIdx.x;
    int tb = (int)thr[img];
    const float* row = logits + ((size_t)img * P + p) * C;
    float r[C], m, l;
    row_lse(row, r, m, l);
#pragma unroll
    for (int c = 1; c < C; ++c) {
        float sc = (r[c] - m) - l;
        if (score_bin(sc) >= tb) {
            unsigned pos = atomicAdd(&cnt[img], 1u);
            if (pos < CAND_MAX) {
                cval[(size_t)img * CAND_MAX + pos] = sc;
                cidx[(size_t)img * CAND_MAX + pos] = (unsigned)(p * CM1 + (c - 1));
            }
        }
    }
}

__global__ __launch_bounds__(512) void k_sort_select(const float* __restrict__ cval,
                                                     const unsigned* __restrict__ cidx,
                                                     const unsigned* __restrict__ cnt,
                                                     float* __restrict__ sval,
                                                     unsigned* __restrict__ sidx) {
    __shared__ float v[CAND_MAX];
    __shared__ unsigned ix[CAND_MAX];
    int img = blockIdx.x;
    unsigned n = cnt[img];
    if (n > CAND_MAX) n = CAND_MAX;
    for (int i = threadIdx.x; i < CAND_MAX; i += 512) {
        if ((unsigned)i < n) {
            v[i] = cval[(size_t)img * CAND_MAX + i];
            ix[i] = cidx[(size_t)img * CAND_MAX + i];
        } else {
            v[i] = -INFINITY;
            ix[i] = 0x7FFFFFFFu;
        }
    }
    __syncthreads();
    // bitonic sort: final order = descending value, ascending index on ties
    for (int k = 2; k <= CAND_MAX; k <<= 1) {
        for (int j = k >> 1; j > 0; j >>= 1) {
            for (int i = threadIdx.x; i < CAND_MAX; i += 512) {
                int l = i ^ j;
                if (l > i) {
                    float va = v[i], vb = v[l];
                    unsigned ia = ix[i], ib = ix[l];
                    bool b_first = (vb > va) || (vb == va && ib < ia);
                    bool a_first = (va > vb) || (va == vb && ia < ib);
                    bool dir = ((i & k) == 0);
                    bool sw = dir ? b_first : a_first;
                    if (sw) { v[i] = vb; v[l] = va; ix[i] = ib; ix[l] = ia; }
                }
            }
            __syncthreads();
        }
    }
    for (int i = threadIdx.x; i < NCAND; i += 512) {
        sval[(size_t)img * NCAND + i] = v[i];
        sidx[(size_t)img * NCAND + i] = ix[i];
    }
}

__global__ __launch_bounds__(256) void k_nms_out(const float* __restrict__ bbox,
                                                 const float* __restrict__ priors,
                                                 const float* __restrict__ sval,
                                                 const unsigned* __restrict__ sidx,
                                                 float* __restrict__ out) {
    __shared__ float x1[NCAND], y1[NCAND], x2[NCAND], y2[NCAND];
    __shared__ float ox1[NCAND], oy1[NCAND], ox2[NCAND], oy2[NCAND];
    __shared__ float sc[NCAND], area[NCAND];
    __shared__ int lab[NCAND];
    __shared__ unsigned long long M[NCAND][NWORDS];
    __shared__ unsigned long long keepw[NWORDS];
    __shared__ float redbuf[256];
    __shared__ float maxc_sh;
    __shared__ int kidx[NOUT];

    int img = blockIdx.x;
    // decode selected boxes
    for (int i = threadIdx.x; i < NCAND; i += 256) {
        unsigned f = sidx[(size_t)img * NCAND + i];
        int p = (int)(f / CM1);
        int c = (int)(f % CM1) + 1;
        const float* lp = bbox + ((size_t)img * P + p) * 4;
        const float* pp = priors + (size_t)p * 4;
        float l0 = lp[0], l1 = lp[1], l2 = lp[2], l3 = lp[3];
        float pcx = pp[0], pcy = pp[1], pw = pp[2], ph = pp[3];
        float cx = l0 * 0.1f * pw + pcx;
        float cy = l1 * 0.1f * ph + pcy;
        float w = expf(l2 * 0.2f) * pw;
        float h = expf(l3 * 0.2f) * ph;
        x1[i] = (cx - w * 0.5f) * IMG_SZ;
        y1[i] = (cy - h * 0.5f) * IMG_SZ;
        x2[i] = (cx + w * 0.5f) * IMG_SZ;
        y2[i] = (cy + h * 0.5f) * IMG_SZ;
        sc[i] = sval[(size_t)img * NCAND + i];
        lab[i] = c;
    }
    __syncthreads();
    // max coordinate over all 1600 values
    float m = -INFINITY;
    for (int i = threadIdx.x; i < NCAND; i += 256) {
        m = fmaxf(m, fmaxf(fmaxf(x1[i], y1[i]), fmaxf(x2[i], y2[i])));
    }
    redbuf[threadIdx.x] = m;
    __syncthreads();
    if (threadIdx.x == 0) {
        float mm = -INFINITY;
        for (int t = 0; t < 256; ++t) mm = fmaxf(mm, redbuf[t]);
        maxc_sh = mm;
    }
    __syncthreads();
    float maxc = maxc_sh;
    for (int i = threadIdx.x; i < NCAND; i += 256) {
        float off = (float)lab[i] * (maxc + 1.0f);
        ox1[i] = x1[i] + off;
        oy1[i] = y1[i] + off;
        ox2[i] = x2[i] + off;
        oy2[i] = y2[i] + off;
        area[i] = (ox2[i] - ox1[i]) * (oy2[i] - oy1[i]);
    }
    __syncthreads();
    // pairwise IoU > thr -> bitmask rows
    for (int i = threadIdx.x; i < NCAND; i += 256) {
        float a1 = ox1[i], b1 = oy1[i], a2 = ox2[i], b2 = oy2[i], ar = area[i];
        for (int w = 0; w < NWORDS; ++w) {
            unsigned long long bits = 0ull;
            int jbase = w * 64;
            int jend = min(64, NCAND - jbase);
            for (int jj = 0; jj < jend; ++jj) {
                int j = jbase + jj;
                float ltx = fmaxf(a1, ox1[j]);
                float lty = fmaxf(b1, oy1[j]);
                float rbx = fminf(a2, ox2[j]);
                float rby = fminf(b2, oy2[j]);
                float iw = fmaxf(rbx - ltx, 0.0f);
                float ih = fmaxf(rby - lty, 0.0f);
                float inter = iw * ih;
                float uni = ar + area[j] - inter;
                float iou = inter / fmaxf(uni, 1e-12f);
                if (iou > NMS_THR) bits |= (1ull << jj);
            }
            M[i][w] = bits;
        }
    }
    __syncthreads();
    // greedy NMS (serial, bitmask) + kidx construction
    if (threadIdx.x == 0) {
        for (int w = 0; w < NWORDS - 1; ++w) keepw[w] = ~0ull;
        keepw[NWORDS - 1] = (1ull << (NCAND - 64 * (NWORDS - 1))) - 1ull;
        for (int i = 0; i < NCAND; ++i) {
            if ((keepw[i >> 6] >> (i & 63)) & 1ull) {
                int iw = i >> 6;
                for (int w = 0; w < NWORDS; ++w) {
                    unsigned long long gm;
                    if (w < iw) gm = 0ull;
                    else if (w > iw) gm = ~0ull;
                    else gm = ((i & 63) == 63) ? 0ull : (~0ull << ((i & 63) + 1));
                    keepw[w] &= ~(M[i][w] & gm);
                }
            }
        }
        int cnt = 0;
        for (int i = 0; i < NCAND && cnt < NOUT; ++i)
            if ((keepw[i >> 6] >> (i & 63)) & 1ull) kidx[cnt++] = i;
        for (int i = 0; i < NCAND && cnt < NOUT; ++i)
            if (!((keepw[i >> 6] >> (i & 63)) & 1ull)) kidx[cnt++] = i;
    }
    __syncthreads();
    // write outputs: boxes [16,100,4] | labels [16,100] | scores [16,100]
    for (int k = threadIdx.x; k < NOUT; k += 256) {
        int i = kidx[k];
        bool kp = (keepw[i >> 6] >> (i & 63)) & 1ull;
        float* ob = out + ((size_t)img * NOUT + k) * 4;
        ob[0] = x1[i];
        ob[1] = y1[i];
        ob[2] = x2[i];
        ob[3] = y2[i];
        out[(size_t)BATCH * NOUT * 4 + (size_t)img * NOUT + k] = (float)lab[i];
        out[(size_t)BATCH * NOUT * 4 + (size_t)BATCH * NOUT + (size_t)img * NOUT + k] =
            kp ? sc[i] : -INFINITY;
    }
}

extern "C" void kernel_launch(void* const* d_in, const int* in_sizes, int n_in,
                              void* d_out, int out_size, void* d_ws, size_t ws_size,
                              hipStream_t stream) {
    const float* logits = (const float*)d_in[0];
    const float* bbox = (const float*)d_in[1];
    const float* priors = (const float*)d_in[2];
    float* out = (float*)d_out;
    char* ws = (char*)d_ws;

    unsigned* hist = (unsigned*)(ws + OFF_HIST);
    unsigned* cnt = (unsigned*)(ws + OFF_CNT);
    unsigned* thr = (unsigned*)(ws + OFF_THR);
    float* cval = (float*)(ws + OFF_CVAL);
    unsigned* cidx = (unsigned*)(ws + OFF_CIDX);
    float* sval = (float*)(ws + OFF_SVAL);
    unsigned* sidx = (unsigned*)(ws + OFF_SIDX);

    // zero histograms + counters (ws is poisoned 0xAA before every launch)
    hipMemsetAsync(ws, 0, OFF_THR, stream);

    dim3 grid(P / 256, BATCH);
    k_score_hist<<<grid, 256, 0, stream>>>(logits, hist);
    k_find_thresh<<<BATCH, 64, 0, stream>>>(hist, thr);
    k_collect<<<grid, 256, 0, stream>>>(logits, thr, cnt, cval, cidx);
    k_sort_select<<<BATCH, 512, 0, stream>>>(cval, cidx, cnt, sval, sidx);
    k_nms_out<<<BATCH, 256, 0, stream>>>(bbox, priors, sval, sidx, out);
}